// Round 12
// baseline (12531.379 us; speedup 1.0000x reference)
//
#include <hip/hip_runtime.h>

// R12: (a) UB-free exact radix-select (pmask/pval prefix compare — R11 had a
// kb>>32 UB that plausibly caused the abort), thread-0 serial bin scan,
// atomic-free bitmask collection; (b) phase-1 fit streaming through 64 KB LDS
// tiles with coalesced float4 loads + XOR-swizzled row reads (<=2-way banks).
// Keys in VGPRs. Phase 2b (fp64 re-key) / 2c (per-column top-K) as in R10.
// Fast-math-proof throughout: integer exponent tests, integer orderings,
// finite sentinels.

#define NQ 16384
#define NF 8192
#define D  64
#define T  32

typedef unsigned int u32;
typedef unsigned long long u64;

#define IDX_INVALID 0xFFFFFFFFu
#define KEY_INVALID 0x7F7FFFFFu       // FLT_MAX bits: present==0 sentinel
#define NANF_BITS   0x7FC00000u

__device__ __forceinline__ int f32_missing(float f) {
    u32 b = __float_as_uint(f);
    return ((b >> 23) & 0xFFu) == 0xFFu;    // NaN/inf => missing
}

__global__ __launch_bounds__(256) void knn_r12(
        const float* __restrict__ X,
        const float* __restrict__ fit,
        const int* __restrict__ pk,
        float* __restrict__ out) {
    __shared__ float4 s_tile[4096];          // 64 KB: 256 rows x 64 floats
    __shared__ u32    s_hist[256];           // 1 KB
    __shared__ u32    s_blw[256];            // below-threshold bitmasks
    __shared__ u32    s_tie[256];            // tie bitmasks
    __shared__ float  s_xv[D];
    __shared__ u32    s_xm[D];
    __shared__ u32    s_ci[T];
    __shared__ double s_kd[T];
    __shared__ float  s_val[D * (T + 1)];    // 8.25 KB
    __shared__ u32    s_sel, s_belowc;

    const int tid = threadIdx.x;
    const int q = blockIdx.x;

    if (tid < D) {
        float xf = X[(size_t)q * D + tid];
        int miss = f32_missing(xf);
        s_xm[tid] = miss ? 0u : 1u;
        s_xv[tid] = miss ? 0.f : xf;
    }
    __syncthreads();

    float xv[D]; u64 xmask = 0;
#pragma unroll
    for (int j = 0; j < D; ++j) {
        xv[j] = s_xv[j];
        xmask |= ((u64)s_xm[j]) << j;
    }

    // ---- phase 1: LDS-staged coalesced streaming; keys -> kb[32] VGPRs ----
    u32 kb[32];
    const float4* fitc = (const float4*)fit;
    for (int tile = 0; tile < 32; ++tile) {
        // stage 256 rows (4096 chunks of 16B) coalesced, XOR-swizzled store
#pragma unroll
        for (int it = 0; it < 16; ++it) {
            int lin = it * 256 + tid;            // chunk within tile
            int r = lin >> 4, m = lin & 15;
            int pos = (r << 4) | (m ^ (r & 15));
            s_tile[pos] = fitc[(size_t)tile * 4096 + lin];
        }
        __syncthreads();

        // each thread computes its row (r = tid) from LDS
        float ssd = 0.f; int pres = 0;
        const int rsw = tid & 15;
#pragma unroll
        for (int mm = 0; mm < 16; ++mm) {
            float4 c = s_tile[(tid << 4) | (mm ^ rsw)];
            float ww[4] = { c.x, c.y, c.z, c.w };
#pragma unroll
            for (int u = 0; u < 4; ++u) {
                int j = mm * 4 + u;
                int ok = (int)((xmask >> j) & 1) & !f32_missing(ww[u]);
                float dm = ok ? (xv[j] - ww[u]) : 0.f;
                ssd = fmaf(dm, dm, ssd);
                pres += ok;
            }
        }
        kb[tile] = (pres > 0) ? __float_as_uint(ssd / (float)pres) : KEY_INVALID;
        __syncthreads();                         // tile consumed; safe to restage
    }

    int K = *pk;
    if (K < 1 || K > 64) {                 // robustness if scalar arrived as float
        float kf = __int_as_float(K);
        K = (kf >= 1.f && kf <= 64.f) ? (int)kf : 5;
    }
    if (K > T) K = T;

    // ---- phase 2a: exact rank-T threshold, 4 byte passes (UB-free) ----
    u32 pmask = 0, pval = 0; int need = T;
    for (int pass = 0; pass < 4; ++pass) {
        const int shift = 24 - pass * 8;
        s_hist[tid] = 0;
        __syncthreads();
#pragma unroll
        for (int i = 0; i < 32; ++i) {
            u32 k = kb[i];
            if ((k & pmask) == pval) atomicAdd(&s_hist[(k >> shift) & 0xFFu], 1u);
        }
        __syncthreads();
        if (tid == 0) {
            u32 run = 0, below = 0; int sel = 255;
            for (int b = 0; b < 256; ++b) {
                u32 c = s_hist[b];
                if (run + c >= (u32)need) { sel = b; below = run; break; }
                run += c;
            }
            if (sel == 255) below = run;        // defensive (cannot trigger)
            s_sel = (u32)sel; s_belowc = below;
        }
        __syncthreads();
        pval |= s_sel << shift;
        pmask |= 0xFFu << shift;
        need -= (int)s_belowc;
        __syncthreads();                        // s_sel reuse next pass
    }
    const u32 thrK = pval;
    const int t_eq = need;                      // # ties to take (smallest idx)

    // ---- phase 2a': atomic-free collection via bitmasks ----
    {
        u32 bb = 0, tb = 0;
#pragma unroll
        for (int i = 0; i < 32; ++i) {
            u32 k = kb[i];
            bb |= (k < thrK)  ? (1u << i) : 0u;
            tb |= (k == thrK) ? (1u << i) : 0u;
        }
        s_blw[tid] = bb; s_tie[tid] = tb;
    }
    __syncthreads();
    if (tid == 0) {
        int n = 0;
        for (int t = 0; t < 256 && n < T; ++t) {
            u32 w = s_blw[t];
            while (w && n < T) {
                int i = __ffs(w) - 1; w &= w - 1;
                s_ci[n++] = (u32)(i * 256 + t);
            }
        }
        // ties: gather (capped), then take t_eq smallest donor indices
        u32 tf[64]; int nt = 0;
        for (int t = 0; t < 256 && nt < 64; ++t) {
            u32 w = s_tie[t];
            while (w && nt < 64) {
                int i = __ffs(w) - 1; w &= w - 1;
                tf[nt++] = (u32)(i * 256 + t);
            }
        }
        for (int j = 0; j < t_eq && j < nt && n < T; ++j) {
            int bp = -1; u32 bi = IDX_INVALID;
            for (int r = 0; r < nt; ++r)
                if (tf[r] < bi) { bi = tf[r]; bp = r; }
            if (bp < 0) break;
            tf[bp] = IDX_INVALID;
            s_ci[n++] = bi;
        }
        for (; n < T; ++n) s_ci[n] = IDX_INVALID;
    }
    __syncthreads();

    // ---- phase 2b: exact fp64 re-key of the T candidates ----
    if (tid < T) {
        u32 ci = s_ci[tid];
        double kd = 1.0e300;
        if (ci != IDX_INVALID) {
            const float* row = fit + (size_t)ci * D;
            double ss = 0.0; int pr = 0;
#pragma unroll
            for (int j = 0; j < D; ++j) {
                float yf = row[j];
                int ok = (int)((xmask >> j) & 1) & !f32_missing(yf);
                double dd = ok ? ((double)xv[j] - (double)yf) : 0.0;
                ss = fma(dd, dd, ss);
                pr += ok;
            }
            kd = (pr > 0) ? (ss / (double)pr) : 1.0e300;
        }
        s_kd[tid] = kd;
    }
    __syncthreads();

    // ---- phase 2c: prefetch candidate values per column (coalesced) ----
    if (tid < D) {
        const int d = tid;
        for (int r = 0; r < T; ++r) {
            u32 ci = s_ci[r];
            float v = (ci != IDX_INVALID) ? fit[(size_t)ci * D + d]
                                          : __uint_as_float(NANF_BITS);
            s_val[d * (T + 1) + r] = v;
        }
    }
    __syncthreads();

    // ---- phase 2d: per-column imputation (64 threads in parallel) ----
    if (tid < D) {
        const int d = tid;
        float res = s_xv[d];
        if (!s_xm[d]) {
            u32 used = 0; float sum = 0.f; int cnt = 0;
            for (int s = 0; s < K; ++s) {
                int best = -1; double bk = 0.0; u32 bi = 0;
                for (int r = 0; r < T; ++r) {
                    if ((used >> r) & 1) continue;
                    u32 ci = s_ci[r];
                    if (ci == IDX_INVALID) continue;
                    float v = s_val[d * (T + 1) + r];
                    if (f32_missing(v)) continue;          // donor missing at d
                    double kdv = s_kd[r];
                    if (kdv >= 1.0e300) continue;
                    if (best < 0 || kdv < bk || (kdv == bk && ci < bi)) {
                        best = r; bk = kdv; bi = ci;
                    }
                }
                if (best < 0) break;
                used |= 1u << best;
                sum += s_val[d * (T + 1) + best];
                cnt++;
            }
            if (cnt > 0) {
                res = sum / (float)cnt;
            } else {
                float cs = 0.f; int cc = 0;    // essentially-never fallback
                for (int f = 0; f < NF; ++f) {
                    float yf = fit[(size_t)f * D + d];
                    if (!f32_missing(yf)) { cs += yf; cc++; }
                }
                res = cc > 0 ? cs / (float)cc : 0.f;
            }
            u32 rb = __float_as_uint(res);
            if (((rb >> 23) & 0xFFu) == 0xFFu) res = 0.f;   // integer guard
        }
        out[(size_t)q * D + d] = res;
    }
}

// ---- launch: single dispatch, no workspace ------------------------------------
extern "C" void kernel_launch(void* const* d_in, const int* in_sizes, int n_in,
                              void* d_out, int out_size, void* d_ws, size_t ws_size,
                              hipStream_t stream) {
    const void* pX = d_in[0];
    const void* pF = (n_in > 1) ? d_in[1] : d_in[0];
    const void* pK = (n_in > 2) ? d_in[2] : d_in[0];
    for (int i = 0; i < n_in; ++i) {
        if (in_sizes[i] == NQ * D)      pX = d_in[i];
        else if (in_sizes[i] == NF * D) pF = d_in[i];
        else if (in_sizes[i] == 1)      pK = d_in[i];
    }
    const float* X   = (const float*)pX;
    const float* fit = (const float*)pF;
    const int*   pk  = (const int*)pK;
    float* out = (float*)d_out;

    knn_r12<<<NQ, 256, 0, stream>>>(X, fit, pk, out);
}